// Round 15
// baseline (215.323 us; speedup 1.0000x reference)
//
#include <hip/hip_runtime.h>
#include <hip/hip_bf16.h>

// ParallelExperts: per-expert LayerNorm -> Linear(1024->4096) -> tanh-GELU
// E=16 experts, 512 tokens each (balanced), fp32 in/out, bf16 MFMA inside.

#define E_EXP 16
#define T_TOK 8192
#define DIN   1024
#define DOUT  4096

typedef __bf16 bf16;
typedef __bf16 bf16x4v __attribute__((ext_vector_type(4)));
typedef __bf16 bf16x8v __attribute__((ext_vector_type(8)));
typedef float  f32x4   __attribute__((ext_vector_type(4)));

typedef __attribute__((address_space(1))) void gvoid;
typedef __attribute__((address_space(3))) void lvoid;

#define SCHED_FENCE __builtin_amdgcn_sched_barrier(0)

// ---------------- LayerNorm -> bf16 (one block per token) ----------------
__global__ __launch_bounds__(256) void ln_bf16_kernel(
    const float* __restrict__ x, const float* __restrict__ gamma,
    const float* __restrict__ beta, bf16* __restrict__ xn) {
  const int t    = blockIdx.x;
  const int e    = t >> 9;            // 512 tokens per expert
  const int tid  = threadIdx.x;
  const float4 xv = reinterpret_cast<const float4*>(x + (size_t)t * DIN)[tid];
  float s  = xv.x + xv.y + xv.z + xv.w;
  float s2 = xv.x * xv.x + xv.y * xv.y + xv.z * xv.z + xv.w * xv.w;
#pragma unroll
  for (int o = 32; o > 0; o >>= 1) {
    s  += __shfl_xor(s,  o, 64);
    s2 += __shfl_xor(s2, o, 64);
  }
  __shared__ float red[8];
  const int lane = tid & 63, wid = tid >> 6;
  if (lane == 0) { red[wid] = s; red[4 + wid] = s2; }
  __syncthreads();
  s  = red[0] + red[1] + red[2] + red[3];
  s2 = red[4] + red[5] + red[6] + red[7];
  const float mu  = s * (1.0f / DIN);
  const float var = s2 * (1.0f / DIN) - mu * mu;
  const float inv = rsqrtf(var + 1e-5f);
  const float4 g = reinterpret_cast<const float4*>(gamma + (size_t)e * DIN)[tid];
  const float4 b = reinterpret_cast<const float4*>(beta  + (size_t)e * DIN)[tid];
  bf16x4v o;
  o[0] = (bf16)((xv.x - mu) * inv * g.x + b.x);
  o[1] = (bf16)((xv.y - mu) * inv * g.y + b.y);
  o[2] = (bf16)((xv.z - mu) * inv * g.z + b.z);
  o[3] = (bf16)((xv.w - mu) * inv * g.w + b.w);
  *reinterpret_cast<bf16x4v*>(xn + (size_t)t * DIN + tid * 4) = o;
}

// ---------------- grouped GEMM: C = GELU(xn @ W[e] + b[e]) ----------------
// 128m x 128n tile, BK=32, FOUR waves (2m x 2n), per-wave 64x64 output
// (acc = 64 VGPR) -- frees registers for DISTANCE-2 B prefetch:
// two 32-dword gather sets, so B(kt) consumed at step kt was issued at
// kt-2 (~2 full K-steps in flight). Little's law: ~16 KB/wave continuously
// in flight -> W streams at multi-TB/s instead of the duty-cycle-starved
// 1.5 TB/s of distance-1 (R5-R14's shared limiter).
// B never touches LDS (register gather + in-register cvt). A staged via
// source-swizzled global_load_lds, triple-buffered at distance 2. One
// barrier per K-step; CVT_B's register dependency is the counted drain
// (drains A(kt)+B(kt), leaves A(kt+1),B(kt+1),B(kt+2-) in flight).
#define BM 128
#define BN 128
#define BK 32
#define NK (DIN / BK)   // 32 K-steps

__global__ __launch_bounds__(256, 2) void grouped_gemm_kernel(
    const bf16* __restrict__ xn, const float* __restrict__ W,
    const float* __restrict__ bias, float* __restrict__ out) {
  __shared__ bf16 Alds[3][BM * BK];   // 3 x 8 KB (A only)

  const int tid    = threadIdx.x;
  const int lane   = tid & 63;
  const int wid    = tid >> 6;       // 0..3
  const int warp_m = wid >> 1;       // 0..1
  const int warp_n = wid & 1;        // 0..1
  const int q      = lane >> 4;      // 0..3 (k-octet of this lane)
  const int lp     = lane & 15;
  const int sw     = (lp >> 1) & 3;  // A frag-read XOR slot

  // XCD swizzle: 2048 blocks, 8 XCDs, 256 contiguous per XCD.
  // XCD x covers mtiles [x*8, x*8+8) (= 2 experts) x all 32 ntiles; the 8
  // consecutive same-ntile blocks share a 1 MB W slice + 2 MB of A panels.
  const int xcd    = blockIdx.x & 7;
  const int s      = blockIdx.x >> 3;      // 0..255
  const int ntile  = s >> 3;               // 0..31
  const int mtile  = xcd * 8 + (s & 7);    // 0..63
  const int e      = mtile >> 2;           // 4 m-tiles per expert
  const int t0     = mtile * BM;
  const int n0     = ntile * BN;

  f32x4 acc[4][4];
#pragma unroll
  for (int i = 0; i < 4; ++i)
#pragma unroll
    for (int j = 0; j < 4; ++j)
      acc[i][j] = (f32x4){0.f, 0.f, 0.f, 0.f};

  const bf16*  Abase = xn + (size_t)t0 * DIN;
  const float* Wexp  = W + (size_t)e * DIN * DOUT + n0;

  // A staging source group (pre-swizzle so linear LDS dest ends up with
  // phys_grp = log_grp ^ ((row>>1)&3); row-within-inst = lane>>2).
  const int akg  = (lane & 3) ^ ((lane >> 3) & 3);
  const int nofs = warp_n * 64 + lp;   // this lane's base n within the panel

  float gB0[32], gB1[32];   // TWO B gather sets (distance-2 pipeline)

#define STAGE_A(buf, k0)                                                      \
  {                                                                           \
    _Pragma("unroll")                                                         \
    for (int c = 0; c < 2; ++c) {                                             \
      const int ci = wid * 2 + c;                  /* 0..7, 16 rows each */   \
      const bf16* g = Abase + (size_t)(ci * 16 + (lane >> 2)) * DIN + (k0) +  \
                      akg * 8;                                                \
      __builtin_amdgcn_global_load_lds((gvoid*)g,                             \
                                       (lvoid*)&Alds[buf][ci * 512], 16, 0, 0); \
    }                                                                         \
  }

// Per-wave B gather into set S: element (ni,j) = W[k0+q*8+j][n0+nofs+ni*16].
// Lanes of one inst: 4 q-groups x 16 consecutive n -> 4x64B segments.
#define GATHER_B(S, k0)                                                       \
  {                                                                           \
    _Pragma("unroll")                                                         \
    for (int j = 0; j < 8; ++j) {                                             \
      const float* wr = Wexp + (size_t)((k0) + q * 8 + j) * DOUT + nofs;      \
      _Pragma("unroll")                                                       \
      for (int ni = 0; ni < 4; ++ni) S[ni * 8 + j] = wr[ni * 16];             \
    }                                                                         \
  }

#define CVT_B(S)                                                              \
  {                                                                           \
    _Pragma("unroll")                                                         \
    for (int ni = 0; ni < 4; ++ni)                                            \
      _Pragma("unroll")                                                       \
      for (int j = 0; j < 8; ++j) bfr[ni][j] = (bf16)S[ni * 8 + j];           \
  }

#define RD_A(AB)                                                              \
  {                                                                           \
    _Pragma("unroll")                                                         \
    for (int mi = 0; mi < 4; ++mi)                                            \
      af[mi] = *reinterpret_cast<const bf16x8v*>(                             \
          &Alds[AB][(warp_m * 64 + mi * 16 + lp) * BK + ((q ^ sw) * 8)]);     \
  }

#define MFMA_ALL                                                              \
  {                                                                           \
    _Pragma("unroll")                                                         \
    for (int mi = 0; mi < 4; ++mi)                                            \
      _Pragma("unroll")                                                       \
      for (int ni = 0; ni < 4; ++ni)                                          \
        acc[mi][ni] = __builtin_amdgcn_mfma_f32_16x16x32_bf16(                \
            af[mi], bfr[ni], acc[mi][ni], 0, 0, 0);                           \
  }

// One K-step. A0_ = current A buf (kt%3), AS_ = stage target ((kt+2)%3).
// SC = B set holding B(KT) (consumed+refilled with B(KT+2)).
// STG: kt<30, LB: kt<30 (B gathers go 2 ahead).
// CVT_B(SC) drains A(KT)+B(KT) (FIFO-older); A(KT+1), B(KT+1) and the new
// B(KT+2) gathers stay in flight across the barrier (counted, no waitcnt).
#define K_STEP(KT, A0_, AS_, SC, STG, LB)                                     \
  {                                                                           \
    bf16x8v af[4], bfr[4];                                                    \
    CVT_B(SC);                                                                \
    SCHED_FENCE;                                                              \
    __builtin_amdgcn_s_barrier();                                             \
    SCHED_FENCE;                                                              \
    RD_A(A0_);                                                                \
    if (LB)  GATHER_B(SC, ((KT) + 2) * BK);                                   \
    if (STG) STAGE_A(AS_, ((KT) + 2) * BK);                                   \
    SCHED_FENCE;                                                              \
    __builtin_amdgcn_s_setprio(1); MFMA_ALL; __builtin_amdgcn_s_setprio(0);   \
  }

  // ---- prologue: FIFO order [A(0)] [B(0)->s0] [A(1)] [B(1)->s1] so step 0's
  // cvt(s0) drains A(0)+B(0) and leaves A(1)+B(1) in flight. ----
  STAGE_A(0, 0);
  SCHED_FENCE;
  GATHER_B(gB0, 0);
  SCHED_FENCE;
  STAGE_A(1, BK);
  SCHED_FENCE;
  GATHER_B(gB1, BK);

  for (int kt = 0; kt < 30; kt += 6) {
    K_STEP(kt,     0, 2, gB0, 1, 1);
    K_STEP(kt + 1, 1, 0, gB1, 1, 1);
    K_STEP(kt + 2, 2, 1, gB0, 1, 1);
    K_STEP(kt + 3, 0, 2, gB1, 1, 1);
    K_STEP(kt + 4, 1, 0, gB0, 1, 1);
    K_STEP(kt + 5, 2, 1, gB1, 1, 1);
  }
  K_STEP(30, 0, 0, gB0, 0, 0);   // consumes B(30); B(31) already in flight
  K_STEP(31, 1, 0, gB1, 0, 0);   // final K-step

  // --- epilogue: + bias, tanh-GELU (jax.nn.gelu approximate=True), fp32 out ---
  // gelu(v) = 0.5 v (1 + tanh(u)) = v / (1 + exp(-2u))
  const float* be = bias + (size_t)e * DOUT;
#pragma unroll
  for (int ni = 0; ni < 4; ++ni) {
    const int col = n0 + warp_n * 64 + ni * 16 + lp;
    const float bc = be[col];
#pragma unroll
    for (int mi = 0; mi < 4; ++mi) {
#pragma unroll
      for (int rr = 0; rr < 4; ++rr) {
        const int row = t0 + warp_m * 64 + mi * 16 + q * 4 + rr;
        float v = acc[mi][ni][rr] + bc;
        const float u = 0.7978845608028654f * (v + 0.044715f * v * v * v);
        v = v / (1.0f + __expf(-2.0f * u));
        out[(size_t)row * DOUT + col] = v;
      }
    }
  }
}

extern "C" void kernel_launch(void* const* d_in, const int* in_sizes, int n_in,
                              void* d_out, int out_size, void* d_ws, size_t ws_size,
                              hipStream_t stream) {
  const float* x     = (const float*)d_in[0];
  // d_in[1] = expert_frequency: balanced by construction (512 each) -> unused
  const float* gamma = (const float*)d_in[2];
  const float* beta  = (const float*)d_in[3];
  const float* W     = (const float*)d_in[4];
  const float* bias  = (const float*)d_in[5];
  float* out = (float*)d_out;
  bf16* xn   = (bf16*)d_ws;    // 8192*1024 bf16 = 16 MiB scratch

  hipLaunchKernelGGL(ln_bf16_kernel, dim3(T_TOK), dim3(256), 0, stream,
                     x, gamma, beta, xn);
  hipLaunchKernelGGL(grouped_gemm_kernel, dim3((T_TOK / BM) * (DOUT / BN)),
                     dim3(256), 0, stream, xn, W, bias, out);
}

// Round 16
// 205.702 us; speedup vs baseline: 1.0468x; 1.0468x over previous
//
#include <hip/hip_runtime.h>
#include <hip/hip_bf16.h>

// ParallelExperts: per-expert LayerNorm -> Linear(1024->4096) -> tanh-GELU
// E=16 experts, 512 tokens each (balanced), fp32 in/out, bf16 MFMA inside.
// R16: W fp32 [k][n] -> bf16 [n][k] transpose PREPASS into d_ws, then a
// fully-symmetric bf16 GEMM where BOTH operands stream via global_load_lds
// (no in-loop cvt / transpose -- the tax that capped R5-R15 at ~13% MfmaUtil).

#define E_EXP 16
#define T_TOK 8192
#define DIN   1024
#define DOUT  4096

typedef __bf16 bf16;
typedef __bf16 bf16x4v __attribute__((ext_vector_type(4)));
typedef __bf16 bf16x8v __attribute__((ext_vector_type(8)));
typedef float  f32x4   __attribute__((ext_vector_type(4)));

typedef __attribute__((address_space(1))) void gvoid;
typedef __attribute__((address_space(3))) void lvoid;

#define SCHED_FENCE __builtin_amdgcn_sched_barrier(0)

// ---------------- LayerNorm -> bf16 (one block per token) ----------------
__global__ __launch_bounds__(256) void ln_bf16_kernel(
    const float* __restrict__ x, const float* __restrict__ gamma,
    const float* __restrict__ beta, bf16* __restrict__ xn) {
  const int t    = blockIdx.x;
  const int e    = t >> 9;            // 512 tokens per expert
  const int tid  = threadIdx.x;
  const float4 xv = reinterpret_cast<const float4*>(x + (size_t)t * DIN)[tid];
  float s  = xv.x + xv.y + xv.z + xv.w;
  float s2 = xv.x * xv.x + xv.y * xv.y + xv.z * xv.z + xv.w * xv.w;
#pragma unroll
  for (int o = 32; o > 0; o >>= 1) {
    s  += __shfl_xor(s,  o, 64);
    s2 += __shfl_xor(s2, o, 64);
  }
  __shared__ float red[8];
  const int lane = tid & 63, wid = tid >> 6;
  if (lane == 0) { red[wid] = s; red[4 + wid] = s2; }
  __syncthreads();
  s  = red[0] + red[1] + red[2] + red[3];
  s2 = red[4] + red[5] + red[6] + red[7];
  const float mu  = s * (1.0f / DIN);
  const float var = s2 * (1.0f / DIN) - mu * mu;
  const float inv = rsqrtf(var + 1e-5f);
  const float4 g = reinterpret_cast<const float4*>(gamma + (size_t)e * DIN)[tid];
  const float4 b = reinterpret_cast<const float4*>(beta  + (size_t)e * DIN)[tid];
  bf16x4v o;
  o[0] = (bf16)((xv.x - mu) * inv * g.x + b.x);
  o[1] = (bf16)((xv.y - mu) * inv * g.y + b.y);
  o[2] = (bf16)((xv.z - mu) * inv * g.z + b.z);
  o[3] = (bf16)((xv.w - mu) * inv * g.w + b.w);
  *reinterpret_cast<bf16x4v*>(xn + (size_t)t * DIN + tid * 4) = o;
}

// ------------- prepass: W fp32 [e][k][n] -> Wb bf16 [e][n][k] -------------
// Tile 32k x 256n per block (8192 blocks, 256 thr). Read coalesced along n,
// LDS transpose ([32][257] pad -> conflict-free column reads), write 64 B
// of k-contiguous bf16 per thread (one full cache line each, zero waste).
__global__ __launch_bounds__(256) void w_transpose_kernel(
    const float* __restrict__ W, bf16* __restrict__ Wb) {
  __shared__ float tile[32][257];
  const int bx = blockIdx.x;
  const int e  = bx >> 9;            // 512 tiles per expert
  const int kt = (bx >> 4) & 31;
  const int nt = bx & 15;
  const int k0 = kt * 32, n0 = nt * 256;
  const int t  = threadIdx.x;
  const int r  = t >> 3;             // row 0..31 (8 threads per row)
  const int c0 = (t & 7) * 32;       // 32 floats per thread
  const float* src = W + ((size_t)e * DIN + k0 + r) * DOUT + n0 + c0;
#pragma unroll
  for (int i = 0; i < 8; ++i) {
    const float4 v = *reinterpret_cast<const float4*>(src + i * 4);
    tile[r][c0 + i * 4 + 0] = v.x;
    tile[r][c0 + i * 4 + 1] = v.y;
    tile[r][c0 + i * 4 + 2] = v.z;
    tile[r][c0 + i * 4 + 3] = v.w;
  }
  __syncthreads();
  bf16* dst = Wb + ((size_t)e * DOUT + n0 + t) * DIN + k0;
#pragma unroll
  for (int j = 0; j < 4; ++j) {
    bf16x8v o;
#pragma unroll
    for (int rr = 0; rr < 8; ++rr) o[rr] = (bf16)tile[j * 8 + rr][t];
    *reinterpret_cast<bf16x8v*>(dst + j * 8) = o;
  }
}

// ------------- main GEMM: C = GELU(xn @ Wb^T + b), both bf16 -------------
// 256x256 tile, BK=32, 8 waves (2m x 4n), per-wave 128x64 (acc = 128).
// A [m][k] and B=Wb [n][k] staged IDENTICALLY: source-XOR-swizzled
// global_load_lds (2 insts/wave each), 3 buffers, stage distance 2.
// One vmcnt(4)+barrier per K-step: tile kt+1's 8 DMA insts stay in flight
// across every barrier (counted, never drained until the tail).
#define BM 256
#define BN 256
#define BK 32
#define NK (DIN / BK)   // 32 K-steps

__global__ __launch_bounds__(512, 2) void gemm_bf16_kernel(
    const bf16* __restrict__ xn, const bf16* __restrict__ Wb,
    const float* __restrict__ bias, float* __restrict__ out) {
  __shared__ bf16 Alds[3][BM * BK];   // 3 x 16 KB
  __shared__ bf16 Blds[3][BN * BK];   // 3 x 16 KB

  const int tid    = threadIdx.x;
  const int lane   = tid & 63;
  const int wid    = tid >> 6;       // 0..7
  const int warp_m = wid >> 2;       // 0..1
  const int warp_n = wid & 3;        // 0..3
  const int q      = lane >> 4;      // 0..3 (k-octet)
  const int lp     = lane & 15;
  const int sw     = (lp >> 1) & 3;  // frag-read XOR slot

  // bijective XCD swizzle: 512 blocks, 8 XCDs, 64 contiguous per XCD.
  const int swz    = (blockIdx.x & 7) * 64 + (blockIdx.x >> 3);
  const int ntile  = swz & 15;       // 0..15
  const int mtile  = swz >> 4;       // 0..31
  const int e      = mtile >> 1;     // 2 m-tiles per expert
  const int t0     = mtile * BM;
  const int n0     = ntile * BN;

  f32x4 acc[8][4];
#pragma unroll
  for (int i = 0; i < 8; ++i)
#pragma unroll
    for (int j = 0; j < 4; ++j)
      acc[i][j] = (f32x4){0.f, 0.f, 0.f, 0.f};

  const bf16* Abase = xn + (size_t)t0 * DIN;
  const bf16* Bbase = Wb + ((size_t)e * DOUT + n0) * DIN;

  // source group pre-swizzle: LDS phys_grp = log_grp ^ ((row>>1)&3)
  const int akg = (lane & 3) ^ ((lane >> 3) & 3);

#define STAGE_A(buf, k0)                                                      \
  {                                                                           \
    _Pragma("unroll")                                                         \
    for (int c = 0; c < 2; ++c) {                                             \
      const int ci = wid * 2 + c;                   /* 0..15, 16 rows each */ \
      const bf16* g = Abase + (size_t)(ci * 16 + (lane >> 2)) * DIN + (k0) +  \
                      akg * 8;                                                \
      __builtin_amdgcn_global_load_lds((gvoid*)g,                             \
                                       (lvoid*)&Alds[buf][ci * 512], 16, 0, 0); \
    }                                                                         \
  }

#define STAGE_B(buf, k0)                                                      \
  {                                                                           \
    _Pragma("unroll")                                                         \
    for (int c = 0; c < 2; ++c) {                                             \
      const int ci = wid * 2 + c;                   /* 0..15, 16 n-rows */    \
      const bf16* g = Bbase + (size_t)(ci * 16 + (lane >> 2)) * DIN + (k0) +  \
                      akg * 8;                                                \
      __builtin_amdgcn_global_load_lds((gvoid*)g,                             \
                                       (lvoid*)&Blds[buf][ci * 512], 16, 0, 0); \
    }                                                                         \
  }

#define RD_AB(AB)                                                             \
  {                                                                           \
    _Pragma("unroll")                                                         \
    for (int mi = 0; mi < 8; ++mi)                                            \
      af[mi] = *reinterpret_cast<const bf16x8v*>(                             \
          &Alds[AB][(warp_m * 128 + mi * 16 + lp) * BK + ((q ^ sw) * 8)]);    \
    _Pragma("unroll")                                                         \
    for (int ni = 0; ni < 4; ++ni)                                            \
      bfr[ni] = *reinterpret_cast<const bf16x8v*>(                            \
          &Blds[AB][(warp_n * 64 + ni * 16 + lp) * BK + ((q ^ sw) * 8)]);     \
  }

#define MFMA_ALL                                                              \
  {                                                                           \
    _Pragma("unroll")                                                         \
    for (int mi = 0; mi < 8; ++mi)                                            \
      _Pragma("unroll")                                                       \
      for (int ni = 0; ni < 4; ++ni)                                          \
        acc[mi][ni] = __builtin_amdgcn_mfma_f32_16x16x32_bf16(                \
            af[mi], bfr[ni], acc[mi][ni], 0, 0, 0);                           \
  }

// One K-step. AB = current buf (kt%3), AS = stage target ((kt+2)%3).
// Top-of-step: vmcnt(VM) then barrier. Steady VM=4: drains tile kt's 4
// DMA insts (this wave), leaves tile kt+1's 4 in flight.
#define K_STEP(KT, AB, AS, STG, VM)                                           \
  {                                                                           \
    bf16x8v af[8], bfr[4];                                                    \
    SCHED_FENCE;                                                              \
    asm volatile("s_waitcnt vmcnt(" #VM ")" ::: "memory");                    \
    __builtin_amdgcn_s_barrier();                                             \
    SCHED_FENCE;                                                              \
    RD_AB(AB);                                                                \
    if (STG) { STAGE_A(AS, ((KT) + 2) * BK); STAGE_B(AS, ((KT) + 2) * BK); }  \
    SCHED_FENCE;                                                              \
    __builtin_amdgcn_s_setprio(1); MFMA_ALL; __builtin_amdgcn_s_setprio(0);   \
  }

  // ---- prologue: stage tiles 0 and 1 (8 DMA insts/wave in flight) ----
  STAGE_A(0, 0);      STAGE_B(0, 0);
  STAGE_A(1, BK);     STAGE_B(1, BK);

  for (int kt = 0; kt < 30; kt += 3) {
    K_STEP(kt,     0, 2, 1, 4);
    K_STEP(kt + 1, 1, 0, 1, 4);
    K_STEP(kt + 2, 2, 1, 1, 4);
  }
  K_STEP(30, 0, 0, 0, 4);   // drains t30; t31 stays in flight
  K_STEP(31, 1, 0, 0, 0);   // final: drain t31

  // --- epilogue: + bias, tanh-GELU (jax.nn.gelu approximate=True) ---
  // gelu(v) = 0.5 v (1 + tanh(u)) = v / (1 + exp(-2u))
  const float* be = bias + (size_t)e * DOUT;
#pragma unroll
  for (int ni = 0; ni < 4; ++ni) {
    const int col = n0 + warp_n * 64 + ni * 16 + lp;
    const float bc = be[col];
#pragma unroll
    for (int mi = 0; mi < 8; ++mi) {
#pragma unroll
      for (int rr = 0; rr < 4; ++rr) {
        const int row = t0 + warp_m * 128 + mi * 16 + q * 4 + rr;
        float v = acc[mi][ni][rr] + bc;
        const float u = 0.7978845608028654f * (v + 0.044715f * v * v * v);
        v = v / (1.0f + __expf(-2.0f * u));
        out[(size_t)row * DOUT + col] = v;
      }
    }
  }
}

// ------------- FALLBACK GEMM (R11, fp32 W in-loop) if ws too small -------------
__global__ __launch_bounds__(512, 2) void gemm_fp32w_kernel(
    const bf16* __restrict__ xn, const float* __restrict__ W,
    const float* __restrict__ bias, float* __restrict__ out) {
  __shared__ bf16 Alds[3][BM * BK];

  const int tid    = threadIdx.x;
  const int lane   = tid & 63;
  const int wid    = tid >> 6;
  const int warp_m = wid >> 2;
  const int warp_n = wid & 3;
  const int q      = lane >> 4;
  const int lp     = lane & 15;
  const int sw     = (lp >> 1) & 3;

  const int swz    = (blockIdx.x & 7) * 64 + (blockIdx.x >> 3);
  const int ntile  = swz & 15;
  const int mtile  = swz >> 4;
  const int e      = mtile >> 1;
  const int t0     = mtile * BM;
  const int n0     = ntile * BN;

  f32x4 acc[8][4];
#pragma unroll
  for (int i = 0; i < 8; ++i)
#pragma unroll
    for (int j = 0; j < 4; ++j)
      acc[i][j] = (f32x4){0.f, 0.f, 0.f, 0.f};

  const bf16*  Abase = xn + (size_t)t0 * DIN;
  const float* Wexp  = W + (size_t)e * DIN * DOUT + n0;
  const int akg  = (lane & 3) ^ ((lane >> 3) & 3);
  const int nofs = warp_n * 64 + lp;
  float gB[32];

#define F_STAGE_A(buf, k0)                                                    \
  {                                                                           \
    _Pragma("unroll")                                                         \
    for (int c = 0; c < 2; ++c) {                                             \
      const int ci = wid * 2 + c;                                             \
      const bf16* g = Abase + (size_t)(ci * 16 + (lane >> 2)) * DIN + (k0) +  \
                      akg * 8;                                                \
      __builtin_amdgcn_global_load_lds((gvoid*)g,                             \
                                       (lvoid*)&Alds[buf][ci * 512], 16, 0, 0); \
    }                                                                         \
  }
#define F_GATHER_B(k0)                                                        \
  {                                                                           \
    _Pragma("unroll")                                                         \
    for (int j = 0; j < 8; ++j) {                                             \
      const float* wr = Wexp + (size_t)((k0) + q * 8 + j) * DOUT + nofs;      \
      _Pragma("unroll")                                                       \
      for (int ni = 0; ni < 4; ++ni) gB[ni * 8 + j] = wr[ni * 16];            \
    }                                                                         \
  }
#define F_K_STEP(KT, A0_, AS_, STG, LB)                                       \
  {                                                                           \
    bf16x8v af[8], bfr[4];                                                    \
    _Pragma("unroll")                                                         \
    for (int ni = 0; ni < 4; ++ni)                                            \
      _Pragma("unroll")                                                       \
      for (int j = 0; j < 8; ++j) bfr[ni][j] = (bf16)gB[ni * 8 + j];          \
    SCHED_FENCE;                                                              \
    __builtin_amdgcn_s_barrier();                                             \
    SCHED_FENCE;                                                              \
    _Pragma("unroll")                                                         \
    for (int mi = 0; mi < 8; ++mi)                                            \
      af[mi] = *reinterpret_cast<const bf16x8v*>(                             \
          &Alds[A0_][(warp_m * 128 + mi * 16 + lp) * BK + ((q ^ sw) * 8)]);   \
    if (LB)  F_GATHER_B(((KT) + 1) * BK);                                     \
    if (STG) F_STAGE_A(AS_, ((KT) + 2) * BK);                                 \
    SCHED_FENCE;                                                              \
    __builtin_amdgcn_s_setprio(1);                                            \
    _Pragma("unroll")                                                         \
    for (int mi = 0; mi < 8; ++mi)                                            \
      _Pragma("unroll")                                                       \
      for (int ni = 0; ni < 4; ++ni)                                          \
        acc[mi][ni] = __builtin_amdgcn_mfma_f32_16x16x32_bf16(                \
            af[mi], bfr[ni], acc[mi][ni], 0, 0, 0);                           \
    __builtin_amdgcn_s_setprio(0);                                            \
  }

  F_STAGE_A(0, 0);
  SCHED_FENCE;
  F_GATHER_B(0);
  SCHED_FENCE;
  F_STAGE_A(1, BK);

  for (int kt = 0; kt < 30; kt += 3) {
    F_K_STEP(kt,     0, 2, 1, 1);
    F_K_STEP(kt + 1, 1, 0, 1, 1);
    F_K_STEP(kt + 2, 2, 1, 1, 1);
  }
  F_K_STEP(30, 0, 0, 0, 1);
  F_K_STEP(31, 1, 0, 0, 0);

  const float* be = bias + (size_t)e * DOUT;
#pragma unroll
  for (int ni = 0; ni < 4; ++ni) {
    const int col = n0 + warp_n * 64 + ni * 16 + lp;
    const float bc = be[col];
#pragma unroll
    for (int mi = 0; mi < 8; ++mi) {
#pragma unroll
      for (int rr = 0; rr < 4; ++rr) {
        const int row = t0 + warp_m * 128 + mi * 16 + q * 4 + rr;
        float v = acc[mi][ni][rr] + bc;
        const float u = 0.7978845608028654f * (v + 0.044715f * v * v * v);
        v = v / (1.0f + __expf(-2.0f * u));
        out[(size_t)row * DOUT + col] = v;
      }
    }
  }
}

extern "C" void kernel_launch(void* const* d_in, const int* in_sizes, int n_in,
                              void* d_out, int out_size, void* d_ws, size_t ws_size,
                              hipStream_t stream) {
  const float* x     = (const float*)d_in[0];
  // d_in[1] = expert_frequency: balanced by construction (512 each) -> unused
  const float* gamma = (const float*)d_in[2];
  const float* beta  = (const float*)d_in[3];
  const float* W     = (const float*)d_in[4];
  const float* bias  = (const float*)d_in[5];
  float* out = (float*)d_out;

  const size_t XN_BYTES = (size_t)T_TOK * DIN * 2;             // 16 MiB
  const size_t WB_BYTES = (size_t)E_EXP * DIN * DOUT * 2;      // 128 MiB
  bf16* xn = (bf16*)d_ws;

  if (ws_size >= XN_BYTES + WB_BYTES) {
    bf16* Wb = (bf16*)((char*)d_ws + XN_BYTES);
    hipLaunchKernelGGL(w_transpose_kernel, dim3(E_EXP * 512), dim3(256), 0,
                       stream, W, Wb);
    hipLaunchKernelGGL(ln_bf16_kernel, dim3(T_TOK), dim3(256), 0, stream,
                       x, gamma, beta, xn);
    hipLaunchKernelGGL(gemm_bf16_kernel, dim3((T_TOK / BM) * (DOUT / BN)),
                       dim3(512), 0, stream, xn, Wb, bias, out);
  } else {
    hipLaunchKernelGGL(ln_bf16_kernel, dim3(T_TOK), dim3(256), 0, stream,
                       x, gamma, beta, xn);
    hipLaunchKernelGGL(gemm_fp32w_kernel, dim3((T_TOK / BM) * (DOUT / BN)),
                       dim3(512), 0, stream, xn, W, bias, out);
  }
}